// Round 5
// baseline (427.745 us; speedup 1.0000x reference)
//
#include <hip/hip_runtime.h>

// GCN 4-layer forward on MI355X.
// Reference: h' = relu( norm_dst * segsum_{dst}( ((h*norm_src) @ W)[src] ) + b )
//
// Round 5: fix round-4 spill — __launch_bounds__(256,2) so wk[32] float2 +
// acc[32] fit in VGPRs (r4: bound=4 capped at 64 regs, spilled, WRITE_SIZE
// +22MB scratch). Gather: 4 edges in flight per slot (was 2).

namespace {

constexpr int NN = 50000;      // nodes
constexpr int NE = 600000;     // edges
constexpr int INDIM = 128;
constexpr int SCAN_BLK = 256;
constexpr int NBLK = (NN + SCAN_BLK - 1) / SCAN_BLK;  // 196

__global__ void deg_kernel(const int* __restrict__ src, const int* __restrict__ dst,
                           int* __restrict__ dego, int* __restrict__ degi) {
  int e = blockIdx.x * blockDim.x + threadIdx.x;
  if (e < NE) {
    atomicAdd(&dego[src[e]], 1);
    atomicAdd(&degi[dst[e]], 1);
  }
}

__global__ void norm_kernel(const int* __restrict__ dego, const int* __restrict__ degi,
                            float* __restrict__ ns, float* __restrict__ nd) {
  int i = blockIdx.x * blockDim.x + threadIdx.x;
  if (i < NN) {
    int a = dego[i]; if (a < 1) a = 1;
    int b = degi[i]; if (b < 1) b = 1;
    ns[i] = 1.0f / sqrtf((float)a);
    nd[i] = 1.0f / sqrtf((float)b);
  }
}

// --- 3-phase scan of deg_in[NN] -> rowptr[NN+1] (exclusive), cursor = rowptr ---

__global__ __launch_bounds__(SCAN_BLK) void scan_phase1(const int* __restrict__ deg,
                                                        int* __restrict__ bsum) {
  __shared__ int ws[SCAN_BLK / 64];
  int i = blockIdx.x * SCAN_BLK + threadIdx.x;
  int v = (i < NN) ? deg[i] : 0;
#pragma unroll
  for (int off = 32; off; off >>= 1) v += __shfl_down(v, off, 64);
  int lane = threadIdx.x & 63, w = threadIdx.x >> 6;
  if (lane == 0) ws[w] = v;
  __syncthreads();
  if (threadIdx.x == 0) {
    int s = 0;
#pragma unroll
    for (int k = 0; k < SCAN_BLK / 64; ++k) s += ws[k];
    bsum[blockIdx.x] = s;
  }
}

__global__ __launch_bounds__(256) void scan_phase2(const int* __restrict__ bsum,
                                                   int* __restrict__ bpre,
                                                   int* __restrict__ rowptr) {
  __shared__ int s[256];
  int t = threadIdx.x;
  int v = (t < NBLK) ? bsum[t] : 0;
  s[t] = v;
  __syncthreads();
  for (int off = 1; off < 256; off <<= 1) {
    int u = (t >= off) ? s[t - off] : 0;
    __syncthreads();
    s[t] += u;
    __syncthreads();
  }
  if (t < NBLK) bpre[t] = s[t] - v;  // exclusive
  if (t == 255) rowptr[NN] = s[255]; // total == NE
}

__global__ __launch_bounds__(SCAN_BLK) void scan_phase3(const int* __restrict__ deg,
                                                        const int* __restrict__ bpre,
                                                        int* __restrict__ rowptr,
                                                        int* __restrict__ cursor) {
  __shared__ int s[SCAN_BLK];
  int t = threadIdx.x;
  int i = blockIdx.x * SCAN_BLK + t;
  int v = (i < NN) ? deg[i] : 0;
  s[t] = v;
  __syncthreads();
  for (int off = 1; off < SCAN_BLK; off <<= 1) {
    int u = (t >= off) ? s[t - off] : 0;
    __syncthreads();
    s[t] += u;
    __syncthreads();
  }
  if (i < NN) {
    int ex = bpre[blockIdx.x] + s[t] - v;
    rowptr[i] = ex;
    cursor[i] = ex;
  }
}

__global__ void fill_kernel(const int* __restrict__ src, const int* __restrict__ dst,
                            int* __restrict__ cursor, int* __restrict__ col) {
  int e = blockIdx.x * blockDim.x + threadIdx.x;
  if (e < NE) {
    int pos = atomicAdd(&cursor[dst[e]], 1);
    col[pos] = src[e];
  }
}

// x[row][j] = ns[row] * sum_k h[row][k] * W[k][j]     (K = 128 always)
//
// Thread layout (256 threads):
//   DO=128: jg = tid>>2 (64 col-pairs), s = tid&3 (4-way k-split), 16 rows/thread
//   DO=64:  rs = tid>>7 (2 row-halves), jg = (tid>>2)&31, s = tid&3, 8 rows/thread
// Thread's k set: k = i*16 + s*4 + kk — s-interleaved so the 4 s-lanes read 16
// distinct LDS banks per ds_read_b128 (verified 0 conflicts in r4 profile).
// W[k][j0..j0+1] in 32 float2 VGPRs (64 regs) + 32 acc regs => needs ~110
// VGPRs: launch_bounds min-waves MUST be 2 (cap 256), not 4 (cap 128->spill).
template <int DO>
__global__ __launch_bounds__(256, 2) void gemm_ns(const float* __restrict__ h,
                                                  const float* __restrict__ W,
                                                  const float* __restrict__ ns,
                                                  float* __restrict__ x) {
  constexpr int RG = 16;                    // rows staged per group (50000%16==0)
  constexpr int RT = (DO == 128) ? 16 : 8;  // rows accumulated per thread
  constexpr int SPT = RT / 4;               // rows stored per thread
  const int tid = threadIdx.x;
  const int s = tid & 3;
  const int jg = (DO == 128) ? (tid >> 2) : ((tid >> 2) & 31);
  const int j0 = jg * 2;
  const int r0t = (DO == 128) ? 0 : (tid >> 7) * 8;

  // W columns j0, j0+1 for this thread's 32 k values
  float2 wk[32];
#pragma unroll
  for (int i = 0; i < 8; ++i)
#pragma unroll
    for (int kk = 0; kk < 4; ++kk) {
      int k = i * 16 + s * 4 + kk;
      wk[i * 4 + kk] = *reinterpret_cast<const float2*>(&W[k * DO + j0]);
    }

  __shared__ __align__(16) float hsf[RG * INDIM];
  __shared__ float nss[RG];

  const int ngroups = NN / RG;  // 3125
  for (int g = blockIdx.x; g < ngroups; g += gridDim.x) {
    const int row0 = g * RG;
    // stage 16 rows (2048 floats) + ns
    {
      const float4* src4 = reinterpret_cast<const float4*>(h + (size_t)row0 * INDIM);
      float4* dst4 = reinterpret_cast<float4*>(hsf);
      dst4[tid] = src4[tid];
      dst4[tid + 256] = src4[tid + 256];
      if (tid < RG) nss[tid] = ns[row0 + tid];
    }
    __syncthreads();

    float acc0[RT], acc1[RT];
#pragma unroll
    for (int r = 0; r < RT; ++r) { acc0[r] = 0.f; acc1[r] = 0.f; }

#pragma unroll
    for (int r = 0; r < RT; ++r) {
      const float* hrow = &hsf[(r0t + r) * INDIM + s * 4];
#pragma unroll
      for (int i = 0; i < 8; ++i) {
        float4 hv = *reinterpret_cast<const float4*>(hrow + i * 16);
        float2 w0 = wk[i * 4 + 0], w1 = wk[i * 4 + 1];
        float2 w2 = wk[i * 4 + 2], w3 = wk[i * 4 + 3];
        acc0[r] = fmaf(hv.x, w0.x, acc0[r]); acc1[r] = fmaf(hv.x, w0.y, acc1[r]);
        acc0[r] = fmaf(hv.y, w1.x, acc0[r]); acc1[r] = fmaf(hv.y, w1.y, acc1[r]);
        acc0[r] = fmaf(hv.z, w2.x, acc0[r]); acc1[r] = fmaf(hv.z, w2.y, acc1[r]);
        acc0[r] = fmaf(hv.w, w3.x, acc0[r]); acc1[r] = fmaf(hv.w, w3.y, acc1[r]);
      }
    }

    // butterfly-reduce the 4 k-partials (lanes differing in bits 0..1)
#pragma unroll
    for (int r = 0; r < RT; ++r) {
      acc0[r] += __shfl_xor(acc0[r], 1, 64);
      acc0[r] += __shfl_xor(acc0[r], 2, 64);
      acc1[r] += __shfl_xor(acc1[r], 1, 64);
      acc1[r] += __shfl_xor(acc1[r], 2, 64);
    }

    // predicated stores: lane s stores rows [s*SPT, (s+1)*SPT) — static indices
#pragma unroll
    for (int r = 0; r < RT; ++r) {
      if ((r / SPT) == s) {
        int row = row0 + r0t + r;
        float sc = nss[r0t + r];
        float2 v;
        v.x = acc0[r] * sc;
        v.y = acc1[r] * sc;
        *reinterpret_cast<float2*>(&x[(size_t)row * DO + j0]) = v;
      }
    }
    __syncthreads();
  }
}

// One wave per node. Lane layout: sub = lane/LPR edge slot, c4 = (lane%LPR)*4
// column. LPR lanes cover a D-dim row with float4; EPW=64/LPR edge slots,
// 4 edges per slot in flight in the main loop (col loads independent of x
// loads of other edges). Slot partials combined by shfl_xor; lanes < LPR
// write the coalesced float4 output with nd/bias/relu fused.
template <int D, bool RELU>
__global__ __launch_bounds__(256) void gather_kernel(const float* __restrict__ x,
                                                     const int* __restrict__ rowptr,
                                                     const int* __restrict__ col,
                                                     const float* __restrict__ nd,
                                                     const float* __restrict__ b,
                                                     float* __restrict__ out) {
  constexpr int LPR = D / 4;     // 32 (D=128) or 16 (D=64)
  constexpr int EPW = 64 / LPR;  // 2 or 4
  const int wid = (blockIdx.x * blockDim.x + threadIdx.x) >> 6;
  const int lane = threadIdx.x & 63;
  if (wid >= NN) return;
  const int sub = lane / LPR;
  const int c4 = (lane % LPR) * 4;
  const int beg = rowptr[wid];
  const int end = rowptr[wid + 1];

  float ax = 0.f, ay = 0.f, az = 0.f, aw = 0.f;
  int e = beg + sub;
  for (; e + 3 * EPW < end; e += 4 * EPW) {
    int c0 = col[e];
    int c1 = col[e + EPW];
    int c2 = col[e + 2 * EPW];
    int c3 = col[e + 3 * EPW];
    float4 v0 = *reinterpret_cast<const float4*>(&x[(size_t)c0 * D + c4]);
    float4 v1 = *reinterpret_cast<const float4*>(&x[(size_t)c1 * D + c4]);
    float4 v2 = *reinterpret_cast<const float4*>(&x[(size_t)c2 * D + c4]);
    float4 v3 = *reinterpret_cast<const float4*>(&x[(size_t)c3 * D + c4]);
    ax += (v0.x + v1.x) + (v2.x + v3.x);
    ay += (v0.y + v1.y) + (v2.y + v3.y);
    az += (v0.z + v1.z) + (v2.z + v3.z);
    aw += (v0.w + v1.w) + (v2.w + v3.w);
  }
  for (; e < end; e += EPW) {
    int c0 = col[e];
    float4 v0 = *reinterpret_cast<const float4*>(&x[(size_t)c0 * D + c4]);
    ax += v0.x; ay += v0.y; az += v0.z; aw += v0.w;
  }

  // combine edge slots (lanes differing in the high bits)
#pragma unroll
  for (int off = LPR; off < 64; off <<= 1) {
    ax += __shfl_xor(ax, off, 64);
    ay += __shfl_xor(ay, off, 64);
    az += __shfl_xor(az, off, 64);
    aw += __shfl_xor(aw, off, 64);
  }

  if (lane < LPR) {
    const float s = nd[wid];
    float4 bb = *reinterpret_cast<const float4*>(&b[c4]);
    float4 r;
    r.x = fmaf(ax, s, bb.x);
    r.y = fmaf(ay, s, bb.y);
    r.z = fmaf(az, s, bb.z);
    r.w = fmaf(aw, s, bb.w);
    if (RELU) {
      r.x = fmaxf(r.x, 0.f);
      r.y = fmaxf(r.y, 0.f);
      r.z = fmaxf(r.z, 0.f);
      r.w = fmaxf(r.w, 0.f);
    }
    *reinterpret_cast<float4*>(&out[(size_t)wid * D + c4]) = r;
  }
}

}  // namespace

extern "C" void kernel_launch(void* const* d_in, const int* in_sizes, int n_in,
                              void* d_out, int out_size, void* d_ws, size_t ws_size,
                              hipStream_t stream) {
  const float* h0  = (const float*)d_in[0];
  const int*   src = (const int*)d_in[1];
  const int*   dst = (const int*)d_in[2];
  const float* W0 = (const float*)d_in[3];
  const float* b0 = (const float*)d_in[4];
  const float* W1 = (const float*)d_in[5];
  const float* b1 = (const float*)d_in[6];
  const float* W2 = (const float*)d_in[7];
  const float* b2 = (const float*)d_in[8];
  const float* W3 = (const float*)d_in[9];
  const float* b3 = (const float*)d_in[10];
  float* out = (float*)d_out;

  // workspace layout (256B aligned)
  char* w = (char*)d_ws;
  size_t off = 0;
  auto take = [&](size_t bytes) {
    char* p = w + off;
    off = (off + bytes + 255) & ~size_t(255);
    return p;
  };
  int*   deg_out = (int*)take(NN * 4);   // adjacent: one memset covers both
  int*   deg_in  = (int*)take(NN * 4);
  float* nsrc    = (float*)take(NN * 4);
  float* ndst    = (float*)take(NN * 4);
  int*   rowptr  = (int*)take((NN + 1) * 4);
  int*   cursor  = (int*)take(NN * 4);
  int*   col     = (int*)take(NE * 4);
  int*   bsum    = (int*)take(NBLK * 4);
  int*   bpre    = (int*)take(NBLK * 4);
  float* xbuf    = (float*)take((size_t)NN * 128 * 4);
  float* hbuf    = (float*)take((size_t)NN * 128 * 4);
  (void)ws_size; (void)in_sizes; (void)n_in; (void)out_size;

  // one memset spanning deg_out..deg_in (contiguous, 256B-padded)
  hipMemsetAsync(deg_out, 0, (size_t)((char*)nsrc - (char*)deg_out), stream);

  const int EB = (NE + 255) / 256;
  const int NB = (NN + 255) / 256;
  deg_kernel<<<EB, 256, 0, stream>>>(src, dst, deg_out, deg_in);
  norm_kernel<<<NB, 256, 0, stream>>>(deg_out, deg_in, nsrc, ndst);
  scan_phase1<<<NBLK, SCAN_BLK, 0, stream>>>(deg_in, bsum);
  scan_phase2<<<1, 256, 0, stream>>>(bsum, bpre, rowptr);
  scan_phase3<<<NBLK, SCAN_BLK, 0, stream>>>(deg_in, bpre, rowptr, cursor);
  fill_kernel<<<EB, 256, 0, stream>>>(src, dst, cursor, col);

  const int GEMM_BLOCKS = 1024;
  const int GATHER_BLOCKS = (NN * 64 + 255) / 256;

  // layer 0: h0 -> x -> hbuf (relu)
  gemm_ns<128><<<GEMM_BLOCKS, 256, 0, stream>>>(h0, W0, nsrc, xbuf);
  gather_kernel<128, true><<<GATHER_BLOCKS, 256, 0, stream>>>(xbuf, rowptr, col, ndst, b0, hbuf);
  // layer 1
  gemm_ns<128><<<GEMM_BLOCKS, 256, 0, stream>>>(hbuf, W1, nsrc, xbuf);
  gather_kernel<128, true><<<GATHER_BLOCKS, 256, 0, stream>>>(xbuf, rowptr, col, ndst, b1, hbuf);
  // layer 2
  gemm_ns<128><<<GEMM_BLOCKS, 256, 0, stream>>>(hbuf, W2, nsrc, xbuf);
  gather_kernel<128, true><<<GATHER_BLOCKS, 256, 0, stream>>>(xbuf, rowptr, col, ndst, b2, hbuf);
  // layer 3: no relu, D=64, straight to d_out
  gemm_ns<64><<<GEMM_BLOCKS, 256, 0, stream>>>(hbuf, W3, nsrc, xbuf);
  gather_kernel<64, false><<<GATHER_BLOCKS, 256, 0, stream>>>(xbuf, rowptr, col, ndst, b3, out);
}

// Round 6
// 382.665 us; speedup vs baseline: 1.1178x; 1.1178x over previous
//
#include <hip/hip_runtime.h>

// GCN 4-layer forward on MI355X.
// Reference: h' = relu( norm_dst * segsum_{dst}( ((h*norm_src) @ W)[src] ) + b )
//
// Round 6: GEMM -> classic outer-product LDS tiling (64x64 tile, 4x4/thread,
// h staged transposed). Register demand ~45 (acc16 + vecs) — no allocator
// cliff (r4/r5: register-resident-W demanded ~112, compiler demoted it and
// re-loaded W from cache inside the loop; 54us latency-bound at 26% VALU).

namespace {

constexpr int NN = 50000;      // nodes
constexpr int NE = 600000;     // edges
constexpr int INDIM = 128;
constexpr int SCAN_BLK = 256;
constexpr int NBLK = (NN + SCAN_BLK - 1) / SCAN_BLK;  // 196

__global__ void deg_kernel(const int* __restrict__ src, const int* __restrict__ dst,
                           int* __restrict__ dego, int* __restrict__ degi) {
  int e = blockIdx.x * blockDim.x + threadIdx.x;
  if (e < NE) {
    atomicAdd(&dego[src[e]], 1);
    atomicAdd(&degi[dst[e]], 1);
  }
}

__global__ void norm_kernel(const int* __restrict__ dego, const int* __restrict__ degi,
                            float* __restrict__ ns, float* __restrict__ nd) {
  int i = blockIdx.x * blockDim.x + threadIdx.x;
  if (i < NN) {
    int a = dego[i]; if (a < 1) a = 1;
    int b = degi[i]; if (b < 1) b = 1;
    ns[i] = 1.0f / sqrtf((float)a);
    nd[i] = 1.0f / sqrtf((float)b);
  }
}

// --- 3-phase scan of deg_in[NN] -> rowptr[NN+1] (exclusive), cursor = rowptr ---

__global__ __launch_bounds__(SCAN_BLK) void scan_phase1(const int* __restrict__ deg,
                                                        int* __restrict__ bsum) {
  __shared__ int ws[SCAN_BLK / 64];
  int i = blockIdx.x * SCAN_BLK + threadIdx.x;
  int v = (i < NN) ? deg[i] : 0;
#pragma unroll
  for (int off = 32; off; off >>= 1) v += __shfl_down(v, off, 64);
  int lane = threadIdx.x & 63, w = threadIdx.x >> 6;
  if (lane == 0) ws[w] = v;
  __syncthreads();
  if (threadIdx.x == 0) {
    int s = 0;
#pragma unroll
    for (int k = 0; k < SCAN_BLK / 64; ++k) s += ws[k];
    bsum[blockIdx.x] = s;
  }
}

__global__ __launch_bounds__(256) void scan_phase2(const int* __restrict__ bsum,
                                                   int* __restrict__ bpre,
                                                   int* __restrict__ rowptr) {
  __shared__ int s[256];
  int t = threadIdx.x;
  int v = (t < NBLK) ? bsum[t] : 0;
  s[t] = v;
  __syncthreads();
  for (int off = 1; off < 256; off <<= 1) {
    int u = (t >= off) ? s[t - off] : 0;
    __syncthreads();
    s[t] += u;
    __syncthreads();
  }
  if (t < NBLK) bpre[t] = s[t] - v;  // exclusive
  if (t == 255) rowptr[NN] = s[255]; // total == NE
}

__global__ __launch_bounds__(SCAN_BLK) void scan_phase3(const int* __restrict__ deg,
                                                        const int* __restrict__ bpre,
                                                        int* __restrict__ rowptr,
                                                        int* __restrict__ cursor) {
  __shared__ int s[SCAN_BLK];
  int t = threadIdx.x;
  int i = blockIdx.x * SCAN_BLK + t;
  int v = (i < NN) ? deg[i] : 0;
  s[t] = v;
  __syncthreads();
  for (int off = 1; off < SCAN_BLK; off <<= 1) {
    int u = (t >= off) ? s[t - off] : 0;
    __syncthreads();
    s[t] += u;
    __syncthreads();
  }
  if (i < NN) {
    int ex = bpre[blockIdx.x] + s[t] - v;
    rowptr[i] = ex;
    cursor[i] = ex;
  }
}

__global__ void fill_kernel(const int* __restrict__ src, const int* __restrict__ dst,
                            int* __restrict__ cursor, int* __restrict__ col) {
  int e = blockIdx.x * blockDim.x + threadIdx.x;
  if (e < NE) {
    int pos = atomicAdd(&cursor[dst[e]], 1);
    col[pos] = src[e];
  }
}

// x[row][j] = ns[row] * sum_k h[row][k] * W[k][j]     (K = 128)
//
// Outer-product tiling: 64-row group x 64-col half. 256 threads = 16 rq x 16
// cq; each thread 4 rows x 4 cols. Per k: 1 ds_read_b128 of ht[k][rq*4..+3]
// (4 addrs x 16-lane broadcast, banks 0-15: conflict-free) + 1 ds_read_b128
// of wl[k][cq*4..+3] (16 chunks over all banks: 2-way, free) -> 16 FMAs.
// ht staged TRANSPOSED: lane = row, so LDS writes are 64 consecutive words
// (2-way, free); global read is strided (L2-hot h, acceptable).
template <int DO>
__global__ __launch_bounds__(256, 2) void gemm_ns(const float* __restrict__ h,
                                                  const float* __restrict__ W,
                                                  const float* __restrict__ ns,
                                                  float* __restrict__ x) {
  constexpr int CH = DO / 64;  // col-halves: 2 (DO=128) or 1 (DO=64)
  const int tid = threadIdx.x;
  const int rq = tid >> 4;   // 0..15 -> rows rq*4..rq*4+3
  const int cq = tid & 15;   // 0..15 -> cols cq*4..cq*4+3 (within half)

  __shared__ __align__(16) float ht[128 * 64];  // h^T tile [k][row], 32 KB
  __shared__ __align__(16) float wl[128 * 64];  // W col-half [k][c], 32 KB
  __shared__ float nss[64];

  const int ngroups = (NN + 63) / 64;  // 782 (last group: 16 valid rows)

  for (int ch = 0; ch < CH; ++ch) {
    // stage W col-half: [128][64] from W[k][ch*64 + c]; coalesced, free writes
#pragma unroll
    for (int it = 0; it < 8; ++it) {
      int flat = it * 256 + tid;
      int k = flat >> 4;
      int ci = (flat & 15) * 4;
      *reinterpret_cast<float4*>(&wl[k * 64 + ci]) =
          *reinterpret_cast<const float4*>(&W[k * DO + ch * 64 + ci]);
    }
    __syncthreads();

    for (int g = blockIdx.x; g < ngroups; g += gridDim.x) {
      const int row0 = g * 64;
      // stage h^T: lane handles (row = flat&63, kq = flat>>6); strided global
      // float4 read, 4 b32 LDS writes at ht[kq*4+j][row] (2-way banks, free)
#pragma unroll
      for (int it = 0; it < 8; ++it) {
        int flat = it * 256 + tid;
        int row = flat & 63;
        int kq = flat >> 6;
        int grow = row0 + row;
        float4 hv = make_float4(0.f, 0.f, 0.f, 0.f);
        if (grow < NN)
          hv = *reinterpret_cast<const float4*>(&h[(size_t)grow * INDIM + kq * 4]);
        ht[(kq * 4 + 0) * 64 + row] = hv.x;
        ht[(kq * 4 + 1) * 64 + row] = hv.y;
        ht[(kq * 4 + 2) * 64 + row] = hv.z;
        ht[(kq * 4 + 3) * 64 + row] = hv.w;
      }
      if (tid < 64) {
        int grow = row0 + tid;
        nss[tid] = (grow < NN) ? ns[grow] : 0.f;
      }
      __syncthreads();

      float acc[4][4] = {{0.f}};
#pragma unroll 8
      for (int k = 0; k < 128; ++k) {
        float4 hv = *reinterpret_cast<const float4*>(&ht[k * 64 + rq * 4]);
        float4 wv = *reinterpret_cast<const float4*>(&wl[k * 64 + cq * 4]);
        acc[0][0] = fmaf(hv.x, wv.x, acc[0][0]);
        acc[0][1] = fmaf(hv.x, wv.y, acc[0][1]);
        acc[0][2] = fmaf(hv.x, wv.z, acc[0][2]);
        acc[0][3] = fmaf(hv.x, wv.w, acc[0][3]);
        acc[1][0] = fmaf(hv.y, wv.x, acc[1][0]);
        acc[1][1] = fmaf(hv.y, wv.y, acc[1][1]);
        acc[1][2] = fmaf(hv.y, wv.z, acc[1][2]);
        acc[1][3] = fmaf(hv.y, wv.w, acc[1][3]);
        acc[2][0] = fmaf(hv.z, wv.x, acc[2][0]);
        acc[2][1] = fmaf(hv.z, wv.y, acc[2][1]);
        acc[2][2] = fmaf(hv.z, wv.z, acc[2][2]);
        acc[2][3] = fmaf(hv.z, wv.w, acc[2][3]);
        acc[3][0] = fmaf(hv.w, wv.x, acc[3][0]);
        acc[3][1] = fmaf(hv.w, wv.y, acc[3][1]);
        acc[3][2] = fmaf(hv.w, wv.z, acc[3][2]);
        acc[3][3] = fmaf(hv.w, wv.w, acc[3][3]);
      }

      // epilogue: scale by ns[row], coalesced float4 stores
#pragma unroll
      for (int i = 0; i < 4; ++i) {
        int row = row0 + rq * 4 + i;
        if (row < NN) {
          float sc = nss[rq * 4 + i];
          float4 v;
          v.x = acc[i][0] * sc;
          v.y = acc[i][1] * sc;
          v.z = acc[i][2] * sc;
          v.w = acc[i][3] * sc;
          *reinterpret_cast<float4*>(&x[(size_t)row * DO + ch * 64 + cq * 4]) = v;
        }
      }
      __syncthreads();
    }
  }
}

// One wave per node. Lane layout: sub = lane/LPR edge slot, c4 = (lane%LPR)*4
// column. LPR lanes cover a D-dim row with float4; EPW=64/LPR edge slots,
// 4 edges per slot in flight. Slot partials combined by shfl_xor; lanes < LPR
// write the coalesced float4 output with nd/bias/relu fused.
template <int D, bool RELU>
__global__ __launch_bounds__(256) void gather_kernel(const float* __restrict__ x,
                                                     const int* __restrict__ rowptr,
                                                     const int* __restrict__ col,
                                                     const float* __restrict__ nd,
                                                     const float* __restrict__ b,
                                                     float* __restrict__ out) {
  constexpr int LPR = D / 4;     // 32 (D=128) or 16 (D=64)
  constexpr int EPW = 64 / LPR;  // 2 or 4
  const int wid = (blockIdx.x * blockDim.x + threadIdx.x) >> 6;
  const int lane = threadIdx.x & 63;
  if (wid >= NN) return;
  const int sub = lane / LPR;
  const int c4 = (lane % LPR) * 4;
  const int beg = rowptr[wid];
  const int end = rowptr[wid + 1];

  float ax = 0.f, ay = 0.f, az = 0.f, aw = 0.f;
  int e = beg + sub;
  for (; e + 3 * EPW < end; e += 4 * EPW) {
    int c0 = col[e];
    int c1 = col[e + EPW];
    int c2 = col[e + 2 * EPW];
    int c3 = col[e + 3 * EPW];
    float4 v0 = *reinterpret_cast<const float4*>(&x[(size_t)c0 * D + c4]);
    float4 v1 = *reinterpret_cast<const float4*>(&x[(size_t)c1 * D + c4]);
    float4 v2 = *reinterpret_cast<const float4*>(&x[(size_t)c2 * D + c4]);
    float4 v3 = *reinterpret_cast<const float4*>(&x[(size_t)c3 * D + c4]);
    ax += (v0.x + v1.x) + (v2.x + v3.x);
    ay += (v0.y + v1.y) + (v2.y + v3.y);
    az += (v0.z + v1.z) + (v2.z + v3.z);
    aw += (v0.w + v1.w) + (v2.w + v3.w);
  }
  for (; e < end; e += EPW) {
    int c0 = col[e];
    float4 v0 = *reinterpret_cast<const float4*>(&x[(size_t)c0 * D + c4]);
    ax += v0.x; ay += v0.y; az += v0.z; aw += v0.w;
  }

  // combine edge slots (lanes differing in the high bits)
#pragma unroll
  for (int off = LPR; off < 64; off <<= 1) {
    ax += __shfl_xor(ax, off, 64);
    ay += __shfl_xor(ay, off, 64);
    az += __shfl_xor(az, off, 64);
    aw += __shfl_xor(aw, off, 64);
  }

  if (lane < LPR) {
    const float s = nd[wid];
    float4 bb = *reinterpret_cast<const float4*>(&b[c4]);
    float4 r;
    r.x = fmaf(ax, s, bb.x);
    r.y = fmaf(ay, s, bb.y);
    r.z = fmaf(az, s, bb.z);
    r.w = fmaf(aw, s, bb.w);
    if (RELU) {
      r.x = fmaxf(r.x, 0.f);
      r.y = fmaxf(r.y, 0.f);
      r.z = fmaxf(r.z, 0.f);
      r.w = fmaxf(r.w, 0.f);
    }
    *reinterpret_cast<float4*>(&out[(size_t)wid * D + c4]) = r;
  }
}

}  // namespace

extern "C" void kernel_launch(void* const* d_in, const int* in_sizes, int n_in,
                              void* d_out, int out_size, void* d_ws, size_t ws_size,
                              hipStream_t stream) {
  const float* h0  = (const float*)d_in[0];
  const int*   src = (const int*)d_in[1];
  const int*   dst = (const int*)d_in[2];
  const float* W0 = (const float*)d_in[3];
  const float* b0 = (const float*)d_in[4];
  const float* W1 = (const float*)d_in[5];
  const float* b1 = (const float*)d_in[6];
  const float* W2 = (const float*)d_in[7];
  const float* b2 = (const float*)d_in[8];
  const float* W3 = (const float*)d_in[9];
  const float* b3 = (const float*)d_in[10];
  float* out = (float*)d_out;

  // workspace layout (256B aligned)
  char* w = (char*)d_ws;
  size_t off = 0;
  auto take = [&](size_t bytes) {
    char* p = w + off;
    off = (off + bytes + 255) & ~size_t(255);
    return p;
  };
  int*   deg_out = (int*)take(NN * 4);   // adjacent: one memset covers both
  int*   deg_in  = (int*)take(NN * 4);
  float* nsrc    = (float*)take(NN * 4);
  float* ndst    = (float*)take(NN * 4);
  int*   rowptr  = (int*)take((NN + 1) * 4);
  int*   cursor  = (int*)take(NN * 4);
  int*   col     = (int*)take(NE * 4);
  int*   bsum    = (int*)take(NBLK * 4);
  int*   bpre    = (int*)take(NBLK * 4);
  float* xbuf    = (float*)take((size_t)NN * 128 * 4);
  float* hbuf    = (float*)take((size_t)NN * 128 * 4);
  (void)ws_size; (void)in_sizes; (void)n_in; (void)out_size;

  // one memset spanning deg_out..deg_in (contiguous, 256B-padded)
  hipMemsetAsync(deg_out, 0, (size_t)((char*)nsrc - (char*)deg_out), stream);

  const int EB = (NE + 255) / 256;
  const int NB = (NN + 255) / 256;
  deg_kernel<<<EB, 256, 0, stream>>>(src, dst, deg_out, deg_in);
  norm_kernel<<<NB, 256, 0, stream>>>(deg_out, deg_in, nsrc, ndst);
  scan_phase1<<<NBLK, SCAN_BLK, 0, stream>>>(deg_in, bsum);
  scan_phase2<<<1, 256, 0, stream>>>(bsum, bpre, rowptr);
  scan_phase3<<<NBLK, SCAN_BLK, 0, stream>>>(deg_in, bpre, rowptr, cursor);
  fill_kernel<<<EB, 256, 0, stream>>>(src, dst, cursor, col);

  const int GEMM_BLOCKS = 512;  // 2 blocks/CU (64 KB LDS each)
  const int GATHER_BLOCKS = (NN * 64 + 255) / 256;

  // layer 0: h0 -> x -> hbuf (relu)
  gemm_ns<128><<<GEMM_BLOCKS, 256, 0, stream>>>(h0, W0, nsrc, xbuf);
  gather_kernel<128, true><<<GATHER_BLOCKS, 256, 0, stream>>>(xbuf, rowptr, col, ndst, b0, hbuf);
  // layer 1
  gemm_ns<128><<<GEMM_BLOCKS, 256, 0, stream>>>(hbuf, W1, nsrc, xbuf);
  gather_kernel<128, true><<<GATHER_BLOCKS, 256, 0, stream>>>(xbuf, rowptr, col, ndst, b1, hbuf);
  // layer 2
  gemm_ns<128><<<GEMM_BLOCKS, 256, 0, stream>>>(hbuf, W2, nsrc, xbuf);
  gather_kernel<128, true><<<GATHER_BLOCKS, 256, 0, stream>>>(xbuf, rowptr, col, ndst, b2, hbuf);
  // layer 3: no relu, D=64, straight to d_out
  gemm_ns<64><<<GEMM_BLOCKS, 256, 0, stream>>>(hbuf, W3, nsrc, xbuf);
  gather_kernel<64, false><<<GATHER_BLOCKS, 256, 0, stream>>>(xbuf, rowptr, col, ndst, b3, out);
}